// Round 1
// baseline (30.138 us; speedup 1.0000x reference)
//
#include <hip/hip_runtime.h>

// 3x3 median blur, float32, B=16 C=3 H=512 W=512, zero padding.
// One thread computes 4 horizontally consecutive pixels (float4 load/store).
// Median of 9 via the classic 19-exchange min/max network (Devillard opt_med9).

#define S2(a, b) { float _t = fminf(a, b); b = fmaxf(a, b); a = _t; }

__global__ __launch_bounds__(256) void median3x3_kernel(
    const float* __restrict__ in, float* __restrict__ out) {
    constexpr int H = 512, W = 512;
    // 2 rows per block: tid 0..127 -> row 0, tid 128..255 -> row 1
    const int tid = threadIdx.x;
    const int row_global = blockIdx.x * 2 + (tid >> 7);   // 0 .. B*C*H-1
    const int lane = tid & 127;
    const int x0 = lane << 2;                              // 0, 4, ..., 508

    const int plane = row_global >> 9;        // H = 512
    const int y = row_global & (H - 1);
    const float* base = in + (size_t)plane * H * W;

    // a[dy][0..5] = columns x0-1 .. x0+4 of row y+dy-1 (zeros at pad)
    float a[3][6];
#pragma unroll
    for (int dy = 0; dy < 3; ++dy) {
        const int yy = y + dy - 1;
        if (yy >= 0 && yy < H) {
            const float* rp = base + (size_t)yy * W + x0;
            const float4 v = *reinterpret_cast<const float4*>(rp);
            a[dy][1] = v.x; a[dy][2] = v.y; a[dy][3] = v.z; a[dy][4] = v.w;
            a[dy][0] = (x0 > 0)     ? rp[-1] : 0.0f;
            a[dy][5] = (x0 + 4 < W) ? rp[4]  : 0.0f;
        } else {
            a[dy][0] = a[dy][1] = a[dy][2] = 0.0f;
            a[dy][3] = a[dy][4] = a[dy][5] = 0.0f;
        }
    }

    float res[4];
#pragma unroll
    for (int k = 0; k < 4; ++k) {
        float p0 = a[0][k], p1 = a[0][k + 1], p2 = a[0][k + 2];
        float p3 = a[1][k], p4 = a[1][k + 1], p5 = a[1][k + 2];
        float p6 = a[2][k], p7 = a[2][k + 1], p8 = a[2][k + 2];
        S2(p1, p2); S2(p4, p5); S2(p7, p8);
        S2(p0, p1); S2(p3, p4); S2(p6, p7);
        S2(p1, p2); S2(p4, p5); S2(p7, p8);
        S2(p0, p3); S2(p5, p8); S2(p4, p7);
        S2(p3, p6); S2(p1, p4); S2(p2, p5);
        S2(p4, p7); S2(p4, p2); S2(p6, p4);
        S2(p4, p2);
        res[k] = p4;
    }

    float4 o;
    o.x = res[0]; o.y = res[1]; o.z = res[2]; o.w = res[3];
    *reinterpret_cast<float4*>(out + (size_t)row_global * W + x0) = o;
}

extern "C" void kernel_launch(void* const* d_in, const int* in_sizes, int n_in,
                              void* d_out, int out_size, void* d_ws, size_t ws_size,
                              hipStream_t stream) {
    const float* x = (const float*)d_in[0];
    float* out = (float*)d_out;
    // B*C*H = 16*3*512 = 24576 rows; 2 rows per 256-thread block
    const int nblocks = (16 * 3 * 512) / 2;   // 12288
    median3x3_kernel<<<nblocks, 256, 0, stream>>>(x, out);
}

// Round 2
// 25.843 us; speedup vs baseline: 1.1662x; 1.1662x over previous
//
#include <hip/hip_runtime.h>

// 3x3 median blur, float32, B=16 C=3 H=512 W=512, zero padding.
// Register rolling window: each thread computes 4 cols x 8 rows of output,
// loading 10 rows per 8 produced (1.25x fetch vs 3x for the naive mapping).
// Median of 9 via exact sorted-columns identity:
//   med9 = med3( max3(lo0,lo1,lo2), med3(m0,m1,m2), min3(h0,h1,h2) )
// using gfx950 v_min3_f32 / v_med3_f32 / v_max3_f32 (1 instr each).

#define MIN3(a, b, c) fminf(fminf(a, b), c)
#define MAX3(a, b, c) fmaxf(fmaxf(a, b), c)
#define MED3(a, b, c) __builtin_amdgcn_fmed3f(a, b, c)

constexpr int H = 512, W = 512;
constexpr int RPS = 8;  // rows per strip (per thread)

__device__ __forceinline__ void load6(const float* __restrict__ rowp, int x0,
                                      bool valid, float v[6]) {
    if (valid) {
        const float4 q = *reinterpret_cast<const float4*>(rowp + x0);
        v[1] = q.x; v[2] = q.y; v[3] = q.z; v[4] = q.w;
        v[0] = (x0 > 0)     ? rowp[x0 - 1] : 0.0f;
        v[5] = (x0 + 4 < W) ? rowp[x0 + 4] : 0.0f;
    } else {
        v[0] = v[1] = v[2] = 0.0f;
        v[3] = v[4] = v[5] = 0.0f;
    }
}

__global__ __launch_bounds__(256) void median3x3_kernel(
    const float* __restrict__ in, float* __restrict__ out) {
    const int tid = threadIdx.x;
    const int lane = tid & 127;       // 128 column-groups of 4
    const int strip = tid >> 7;       // 2 strips of 8 rows per block
    const int x0 = lane << 2;         // 0,4,...,508

    const int rg0 = blockIdx.x * (2 * RPS) + strip * RPS;  // first output row (global)
    const int plane = rg0 >> 9;       // H = 512; strips never cross planes (8 | 512)
    const int y0 = rg0 & (H - 1);

    const float* base = in + (size_t)plane * H * W;
    float* obase = out + (size_t)plane * H * W;

    float c0[6], c1[6], c2[6];
    load6(base + (size_t)(y0 - 1) * W, x0, y0 > 0, c0);  // row above (zeros at top)
    load6(base + (size_t)y0 * W, x0, true, c1);          // first output row

#pragma unroll
    for (int r = 0; r < RPS; ++r) {
        const int yn = y0 + r + 1;
        load6(base + (size_t)yn * W, x0, yn < H, c2);    // row below (zeros at bottom)

        // sort each of the 6 columns vertically (3 instrs per column)
        float lo[6], mi[6], hi[6];
#pragma unroll
        for (int j = 0; j < 6; ++j) {
            lo[j] = MIN3(c0[j], c1[j], c2[j]);
            mi[j] = MED3(c0[j], c1[j], c2[j]);
            hi[j] = MAX3(c0[j], c1[j], c2[j]);
        }

        // 4 output pixels from 3 adjacent sorted columns each (4 instrs/pixel)
        float4 o;
        float res[4];
#pragma unroll
        for (int k = 0; k < 4; ++k) {
            const float a = MAX3(lo[k], lo[k + 1], lo[k + 2]);
            const float b = MED3(mi[k], mi[k + 1], mi[k + 2]);
            const float c = MIN3(hi[k], hi[k + 1], hi[k + 2]);
            res[k] = MED3(a, b, c);
        }
        o.x = res[0]; o.y = res[1]; o.z = res[2]; o.w = res[3];
        *reinterpret_cast<float4*>(obase + (size_t)(y0 + r) * W + x0) = o;

        // roll the window (register renaming under full unroll)
#pragma unroll
        for (int j = 0; j < 6; ++j) { c0[j] = c1[j]; c1[j] = c2[j]; }
    }
}

extern "C" void kernel_launch(void* const* d_in, const int* in_sizes, int n_in,
                              void* d_out, int out_size, void* d_ws, size_t ws_size,
                              hipStream_t stream) {
    const float* x = (const float*)d_in[0];
    float* out = (float*)d_out;
    // B*C*H = 24576 rows; 16 rows per block (2 strips x 8 rows)
    const int nblocks = (16 * 3 * H) / (2 * RPS);  // 1536
    median3x3_kernel<<<nblocks, 256, 0, stream>>>(x, out);
}

// Round 3
// 25.546 us; speedup vs baseline: 1.1798x; 1.0116x over previous
//
#include <hip/hip_runtime.h>

// 3x3 median blur, float32, B=16 C=3 H=512 W=512, zero padding.
// One wave (64 lanes) per block; each lane computes 4 cols x 8 rows.
// Halo columns come from cross-lane shuffles (not extra loads); only
// lanes 0/63 do a predicated single-lane edge load.
// Median of 9 = med3( max3(lo), med3(mid), min3(hi) ) over vertically
// sorted column triples (v_min3/v_med3/v_max3, 1 instr each).

#define MIN3(a, b, c) fminf(fminf(a, b), c)
#define MAX3(a, b, c) fmaxf(fmaxf(a, b), c)
#define MED3(a, b, c) __builtin_amdgcn_fmed3f(a, b, c)

constexpr int H = 512, W = 512;
constexpr int RPS = 8;                 // rows per strip (per thread)
constexpr int NBLOCKS = (16 * 3 * H / RPS) * 2;  // 3072 strips * 2 halves = 6144

__device__ __forceinline__ void load_row(const float* __restrict__ rowp, int x0,
                                         int lane, bool valid, float v[6]) {
    if (valid) {
        const float4 q = *reinterpret_cast<const float4*>(rowp + x0);
        float lft = __shfl_up(q.w, 1);    // lane i-1's col x0-1
        float rgt = __shfl_down(q.x, 1);  // lane i+1's col x0+4
        if (lane == 0)  lft = (x0 > 0)     ? rowp[x0 - 1] : 0.0f;
        if (lane == 63) rgt = (x0 + 4 < W) ? rowp[x0 + 4] : 0.0f;
        v[0] = lft; v[1] = q.x; v[2] = q.y; v[3] = q.z; v[4] = q.w; v[5] = rgt;
    } else {
        v[0] = v[1] = v[2] = 0.0f;
        v[3] = v[4] = v[5] = 0.0f;
    }
}

__global__ __launch_bounds__(64) void median3x3_kernel(
    const float* __restrict__ in, float* __restrict__ out) {
    // Bijective XCD swizzle: 6144 blocks, 8 XCDs -> contiguous chunks of 768
    const int braw = blockIdx.x;
    const int bid = (braw & 7) * (NBLOCKS / 8) + (braw >> 3);

    const int half = bid & 1;            // which 256-col half of the row
    const int strip = bid >> 1;          // vertical strip id (8 rows each)
    const int lane = threadIdx.x;        // 0..63
    const int x0 = half * 256 + (lane << 2);

    const int rg0 = strip * RPS;         // first output row (global row index)
    const int plane = rg0 >> 9;          // H = 512; strips never cross planes
    const int y0 = rg0 & (H - 1);

    const float* base = in + (size_t)plane * H * W;
    float* obase = out + (size_t)plane * H * W;

    float c0[6], c1[6], c2[6];
    load_row(base + (size_t)(y0 - 1) * W, x0, lane, y0 > 0, c0);
    load_row(base + (size_t)y0 * W, x0, lane, true, c1);

#pragma unroll
    for (int r = 0; r < RPS; ++r) {
        const int yn = y0 + r + 1;
        load_row(base + (size_t)yn * W, x0, lane, yn < H, c2);

        // vertically sort the 6 columns (3 instrs per column)
        float lo[6], mi[6], hi[6];
#pragma unroll
        for (int j = 0; j < 6; ++j) {
            lo[j] = MIN3(c0[j], c1[j], c2[j]);
            mi[j] = MED3(c0[j], c1[j], c2[j]);
            hi[j] = MAX3(c0[j], c1[j], c2[j]);
        }

        // 4 output pixels, 4 instrs each
        float res[4];
#pragma unroll
        for (int k = 0; k < 4; ++k) {
            const float a = MAX3(lo[k], lo[k + 1], lo[k + 2]);
            const float b = MED3(mi[k], mi[k + 1], mi[k + 2]);
            const float c = MIN3(hi[k], hi[k + 1], hi[k + 2]);
            res[k] = MED3(a, b, c);
        }
        float4 o;
        o.x = res[0]; o.y = res[1]; o.z = res[2]; o.w = res[3];
        *reinterpret_cast<float4*>(obase + (size_t)(y0 + r) * W + x0) = o;

#pragma unroll
        for (int j = 0; j < 6; ++j) { c0[j] = c1[j]; c1[j] = c2[j]; }
    }
}

extern "C" void kernel_launch(void* const* d_in, const int* in_sizes, int n_in,
                              void* d_out, int out_size, void* d_ws, size_t ws_size,
                              hipStream_t stream) {
    const float* x = (const float*)d_in[0];
    float* out = (float*)d_out;
    median3x3_kernel<<<NBLOCKS, 64, 0, stream>>>(x, out);
}